// Round 14
// baseline (293.883 us; speedup 1.0000x reference)
//
#include <hip/hip_runtime.h>
#include <hip/hip_bf16.h>
#include <cstdint>

#define T_    4096
#define HID_  2048
#define DH    128
#define NQ_   16
#define NKV_  4
#define QKVW  3072   // 2048 Q + 512 K + 512 V

typedef __attribute__((ext_vector_type(8))) short bf16x8;
typedef __attribute__((ext_vector_type(4))) float f32x4;
typedef __attribute__((ext_vector_type(16))) float f32x16;
typedef __attribute__((ext_vector_type(4))) float f4;
typedef __attribute__((ext_vector_type(4))) short s4;

__device__ __forceinline__ short f2bf(float f) {
  union { float f; unsigned u; } x; x.f = f;
  unsigned r = x.u + 0x7fffu + ((x.u >> 16) & 1u);
  return (short)(r >> 16);
}
__device__ __forceinline__ float bf2f(short s) {
  return __uint_as_float(((unsigned)(unsigned short)s) << 16);
}
__device__ __forceinline__ unsigned pkbf2(float a, float b) {
  union { __hip_bfloat162 h; unsigned u; } c;
  c.h = __float22bfloat162_rn(make_float2(a, b));
  return c.u;
}

__device__ __forceinline__ void gload16(const void* g, void* l) {
  __builtin_amdgcn_global_load_lds(
      (const __attribute__((address_space(1))) unsigned*)g,
      (__attribute__((address_space(3))) unsigned*)l, 16, 0, 0);
}

#define MFMA16(a, b, c) __builtin_amdgcn_mfma_f32_16x16x32_bf16(a, b, c, 0, 0, 0)
#define MFMA32(a, b, c) __builtin_amdgcn_mfma_f32_32x32x16_bf16(a, b, c, 0, 0, 0)

#define Z16 {0.f,0.f,0.f,0.f,0.f,0.f,0.f,0.f,0.f,0.f,0.f,0.f,0.f,0.f,0.f,0.f}
#define SCL2 0.127517432f  // (1/sqrt(128)) * log2(e), folded into Q at RoPE

// ---------------- single fused fp32 -> bf16 conversion for all 5 tensors ----------------
#define C_HS 2097152u            // hs:  8M elems
#define C_WQ (C_HS + 1048576u)   // wq:  4M
#define C_WK (C_WQ + 262144u)    // wk:  1M
#define C_WV (C_WK + 262144u)    // wv:  1M
#define C_WO (C_WV + 1048576u)   // wo:  4M
__global__ void cvt_all(const float* __restrict__ hs, const float* __restrict__ wq,
                        const float* __restrict__ wk, const float* __restrict__ wv,
                        const float* __restrict__ wo, short* __restrict__ hs_bf,
                        short* __restrict__ w1_bf, short* __restrict__ wo_bf) {
  const unsigned stride = gridDim.x * blockDim.x;
  for (unsigned i = blockIdx.x * blockDim.x + threadIdx.x; i < C_WO; i += stride) {
    const float* s; short* d; unsigned off;
    if (i < C_HS)      { s = hs; d = hs_bf;           off = i; }
    else if (i < C_WQ) { s = wq; d = w1_bf;           off = i - C_HS; }
    else if (i < C_WK) { s = wk; d = w1_bf + 4194304; off = i - C_WQ; }
    else if (i < C_WV) { s = wv; d = w1_bf + 5242880; off = i - C_WK; }
    else               { s = wo; d = wo_bf;           off = i - C_WV; }
    f4 v = ((const f4*)s)[off];
    s4 o;
    o[0] = f2bf(v[0]); o[1] = f2bf(v[1]); o[2] = f2bf(v[2]); o[3] = f2bf(v[3]);
    ((s4*)d)[off] = o;
  }
}

// ---------------- GEMM: C = A (MxK) * B^T, B stored (N,K) row-major ----------------
// 128x128 tile, BK=64. LDS XOR-swizzled via pre-swizzled global_load_lds source.
template <int BF16OUT>
__global__ __launch_bounds__(256) void gemm_bt(const short* __restrict__ A,
                                               const short* __restrict__ B,
                                               void* __restrict__ Cp,
                                               int N, int K) {
  __shared__ short lA[128 * 64];
  __shared__ short lB[128 * 64];
  const int nb = gridDim.x * gridDim.y;
  const int lin = blockIdx.y * gridDim.x + blockIdx.x;
  const int per = nb >> 3;
  const int wg = (lin & 7) * per + (lin >> 3);
  const int bx = wg % gridDim.x;
  const int by = wg / gridDim.x;

  const int tid = threadIdx.x;
  const int lane = tid & 63;
  const int w = tid >> 6;
  const int wr = w >> 1, wc = w & 1;
  const int l15 = lane & 15, l4 = lane >> 4;
  f32x4 acc[4][4];
#pragma unroll
  for (int m = 0; m < 4; m++)
#pragma unroll
    for (int n = 0; n < 4; n++) acc[m][n] = f32x4{0.f, 0.f, 0.f, 0.f};

  const short* Ag = A + (size_t)bx * 128 * K;
  const short* Bg = B + (size_t)by * 128 * K;

  for (int kt = 0; kt < K; kt += 64) {
#pragma unroll
    for (int i = 0; i < 4; ++i) {
      const int cb = i * 256 + w * 64;       // wave-uniform chunk base
      const int c = cb + lane;
      const int row = c >> 3;                // 8 chunks (128B) per row
      const int x = (c & 7) << 4;            // byte col in LDS
      const int sx = x ^ ((row & 7) << 4);   // pre-swizzled source col
      gload16(Ag + (size_t)row * K + kt + (sx >> 1), (char*)lA + cb * 16);
      gload16(Bg + (size_t)row * K + kt + (sx >> 1), (char*)lB + cb * 16);
    }
    __syncthreads();
    bf16x8 af[4][2], bfr[4][2];
#pragma unroll
    for (int m = 0; m < 4; m++) {
      const int row = wr * 64 + m * 16 + l15;
      const int sw = (row & 7) << 4;
#pragma unroll
      for (int kk = 0; kk < 2; kk++)
        af[m][kk] = *(const bf16x8*)((const char*)lA + row * 128 + ((kk * 64 + l4 * 16) ^ sw));
    }
#pragma unroll
    for (int n = 0; n < 4; n++) {
      const int row = wc * 64 + n * 16 + l15;
      const int sw = (row & 7) << 4;
#pragma unroll
      for (int kk = 0; kk < 2; kk++)
        bfr[n][kk] = *(const bf16x8*)((const char*)lB + row * 128 + ((kk * 64 + l4 * 16) ^ sw));
    }
#pragma unroll
    for (int m = 0; m < 4; m++)
#pragma unroll
      for (int n = 0; n < 4; n++) {
        acc[m][n] = MFMA16(af[m][0], bfr[n][0], acc[m][n]);
        acc[m][n] = MFMA16(af[m][1], bfr[n][1], acc[m][n]);
      }
    __syncthreads();
  }

  const int r0 = bx * 128 + wr * 64;
  const int c0 = by * 128 + wc * 64;
#pragma unroll
  for (int m = 0; m < 4; m++)
#pragma unroll
    for (int n = 0; n < 4; n++)
#pragma unroll
      for (int r = 0; r < 4; r++) {
        const int row = r0 + m * 16 + l4 * 4 + r;
        const int col = c0 + n * 16 + l15;
        if (BF16OUT)
          ((short*)Cp)[(size_t)row * N + col] = f2bf(acc[m][n][r]);
        else
          ((float*)Cp)[(size_t)row * N + col] = acc[m][n][r];
      }
}

// ---------------- RoPE v2: per-row LDS sincos table + short4 vector I/O ----------------
__global__ void rope_k(short* __restrict__ qkv, const int* __restrict__ pos) {
  __shared__ float cs[64], sn[64];
  const int row = blockIdx.x;
  const int tid = threadIdx.x;
  if (tid < 64) {
    const float fp = (float)pos[row];
    const float freq = fp * powf(10000.0f, -(float)tid * (1.0f / 64.0f));
    cs[tid] = cosf(freq);
    sn[tid] = sinf(freq);
  }
  __syncthreads();
  const int p = tid * 4;              // pair index: 0..1279
  const int head = p >> 6;            // 0..19 : 16 Q heads then 4 K heads
  const int d0 = p & 63;
  const int col0 = (head < NQ_) ? head * DH : HID_ + (head - NQ_) * DH;
  const float scl = (head < NQ_) ? SCL2 : 1.0f;
  short* q = qkv + (size_t)row * QKVW + col0 + d0;
  s4 x1 = *(const s4*)q;
  s4 x2 = *(const s4*)(q + 64);
  s4 o1, o2;
#pragma unroll
  for (int j = 0; j < 4; j++) {
    const float c = cs[d0 + j], s = sn[d0 + j];
    const float a = bf2f(x1[j]), b = bf2f(x2[j]);
    o1[j] = f2bf((a * c - b * s) * scl);
    o2[j] = f2bf((b * c + a * s) * scl);
  }
  *(s4*)q = o1;
  *(s4*)(q + 64) = o2;
}

// ---------------- causal GQA flash attention (v11: 4-wave blocks, full KV) ----------------
// 512 blocks x 256 threads. Block = (kvh, qb): 4 waves = 4 heads, each wave
// processes ALL kv tiles of qb (no sp split -> no merge, no parity-idle waves).
// LDS 32KB/block -> 4 blocks/CU resident (16 waves) with variable-size blocks
// backfilling (fixes the 21%-occupancy drain of exactly-2/CU equal-slot grids).
// Big qb dispatched first; kvh per XCD-pair for KV L2 locality.

// prefetch kv tile tt into kr[4] (K rows) / vr[4] (V rows, 2 pair-col groups)
#define PRE(tt)                                                                     \
  {                                                                                 \
    const int kv0p = (tt) * 64;                                                     \
    _Pragma("unroll") for (int i = 0; i < 4; i++) {                                 \
      const int c = i * 256 + tid;                                                  \
      const int row = c >> 4, e = (c & 15) << 3;                                    \
      kr[i] = *(const bf16x8*)(kbase + (size_t)(kv0p + row) * QKVW + e);            \
    }                                                                               \
    {                                                                               \
      const int rp = tid >> 4, e = (tid & 15) << 3;                                 \
      vr[0] = *(const bf16x8*)(vbase + (size_t)(kv0p + 2 * rp) * QKVW + e);         \
      vr[1] = *(const bf16x8*)(vbase + (size_t)(kv0p + 2 * rp + 1) * QKVW + e);     \
      vr[2] = *(const bf16x8*)(vbase + (size_t)(kv0p + 2 * rp + 32) * QKVW + e);    \
      vr[3] = *(const bf16x8*)(vbase + (size_t)(kv0p + 2 * rp + 33) * QKVW + e);    \
    }                                                                               \
  }

// write staged regs: K [64][256B] XOR-swz; V^T [128 d][64 kv] pair-col sigma-permuted
#define WRITEBUF()                                                              \
  {                                                                             \
    char* sK_ = smem;                                                           \
    char* sV_ = smem + 16384;                                                   \
    _Pragma("unroll") for (int i = 0; i < 4; i++) {                             \
      const int c = i * 256 + tid;                                              \
      const int row = c >> 4, e16 = (c & 15) << 4;                              \
      const int swz = (((row >> 3) ^ row) & 7) << 4;                            \
      *(bf16x8*)(sK_ + row * 256 + (e16 ^ swz)) = kr[i];                        \
    }                                                                           \
    {                                                                           \
      const int rp = tid >> 4, e = (tid & 15) << 3;                             \
      const int rp2 = (rp & ~6) | ((rp & 2) << 1) | ((rp & 4) >> 1);            \
      _Pragma("unroll") for (int jj = 0; jj < 8; jj++) {                        \
        const int d = e + jj;                                                   \
        const int swz = (((d >> 3) ^ d) & 7) << 4;                              \
        const unsigned p0 = ((unsigned)(unsigned short)vr[0][jj]) |             \
                            (((unsigned)(unsigned short)vr[1][jj]) << 16);      \
        const unsigned p1 = ((unsigned)(unsigned short)vr[2][jj]) |             \
                            (((unsigned)(unsigned short)vr[3][jj]) << 16);      \
        *(unsigned*)(sV_ + d * 128 + ((rp2 * 4) ^ swz)) = p0;                   \
        *(unsigned*)(sV_ + d * 128 + (((rp2 + 16) * 4) ^ swz)) = p1;            \
      }                                                                         \
    }                                                                           \
  }

__global__ __launch_bounds__(256) void attn_k(const short* __restrict__ qkv,
                                              short* __restrict__ aout) {
  __shared__ __align__(16) char smem[32768];  // K 16KB + V^T 16KB

  const int lin = blockIdx.x;                   // 0..511
  const int xcd = lin & 7;
  const int slot = lin >> 3;                    // 0..63
  const int kvh = xcd >> 1;                     // 2 XCDs per kvh
  const int qb = 127 - (slot * 2 + (xcd & 1));  // big blocks dispatched first
  const int tid = threadIdx.x, lane = tid & 63, head = tid >> 6;
  const int hi = lane >> 5, l31 = lane & 31;
  const int h = kvh * 4 + head;

  const short* kbase = qkv + HID_ + kvh * DH;
  const short* vbase = qkv + HID_ + NKV_ * DH + kvh * DH;

  const int qrow0 = qb * 32;
  const int ntiles = qb / 2 + 1;
  const int myq = qrow0 + l31;

  bf16x8 qf[8];
  {
    const short* qp = qkv + (size_t)myq * QKVW + h * DH + hi * 8;
#pragma unroll
    for (int c = 0; c < 8; c++) qf[c] = *(const bf16x8*)(qp + c * 16);
  }
  f32x16 o[4] = {Z16, Z16, Z16, Z16};
  float m = -3e38f, l = 0.f;

  bf16x8 kr[4], vr[4];
  PRE(0)

  for (int t = 0; t < ntiles; ++t) {
    __syncthreads();  // all waves done reading previous tile
    WRITEBUF()
    __syncthreads();  // staged tile visible
    if (t + 1 < ntiles) PRE(t + 1)  // overlaps compute below
    const char* bK = smem;
    const char* bV = smem + 16384;
    const int kv0 = t * 64;

    // ---- S^T = K Q^T : two 32x32 tiles over kv rows (log2 domain) ----
    f32x16 s0 = Z16, s1 = Z16;
    const int sw0 = (((l31 >> 3) ^ l31) & 7) << 4;
    const int r1 = 32 + l31;
    const int sw1 = (((r1 >> 3) ^ r1) & 7) << 4;
    __builtin_amdgcn_s_setprio(1);
#pragma unroll
    for (int c = 0; c < 8; c++) {
      const int co = c * 32 + hi * 16;
      const bf16x8 k0 = *(const bf16x8*)(bK + l31 * 256 + (co ^ sw0));
      const bf16x8 k1 = *(const bf16x8*)(bK + r1 * 256 + (co ^ sw1));
      s0 = MFMA32(k0, qf[c], s0);
      s1 = MFMA32(k1, qf[c], s1);
    }
    __builtin_amdgcn_s_setprio(0);
    // ---- in-register online softmax (lane owns q-row l31) ----
    float sv0[16], sv1[16];
    if (t == ntiles - 1) {
#pragma unroll
      for (int r = 0; r < 16; r++) {
        const int kk = (r & 3) + 8 * (r >> 2) + 4 * hi;
        sv0[r] = (kv0 + kk <= myq) ? s0[r] : -1e30f;
        sv1[r] = (kv0 + 32 + kk <= myq) ? s1[r] : -1e30f;
      }
    } else {
#pragma unroll
      for (int r = 0; r < 16; r++) {
        sv0[r] = s0[r];
        sv1[r] = s1[r];
      }
    }
    float mx[8];
#pragma unroll
    for (int r = 0; r < 8; r++)
      mx[r] = fmaxf(fmaxf(sv0[r], sv0[r + 8]), fmaxf(sv1[r], sv1[r + 8]));
#pragma unroll
    for (int st = 4; st > 0; st >>= 1)
#pragma unroll
      for (int r = 0; r < 4; r++)
        if (r < st) mx[r] = fmaxf(mx[r], mx[r + st]);
    float pm = fmaxf(mx[0], __shfl_xor(mx[0], 32));
    if (__any(pm > m + 11.5f)) {  // defer-max (T13)
      const float mn = fmaxf(m, pm);
      const float al = exp2f(m - mn);
      m = mn;
      l *= al;
#pragma unroll
      for (int r = 0; r < 16; r++) {
        const float ar = __shfl(al, (r & 3) + 8 * (r >> 2) + 4 * hi);
#pragma unroll
        for (int dt = 0; dt < 4; dt++) o[dt][r] *= ar;
      }
    }
    float pv0[16], pv1[16];
#pragma unroll
    for (int r = 0; r < 16; r++) {
      pv0[r] = exp2f(sv0[r] - m);
      pv1[r] = exp2f(sv1[r] - m);
    }
    float sum[8];
#pragma unroll
    for (int r = 0; r < 8; r++)
      sum[r] = (pv0[r] + pv0[r + 8]) + (pv1[r] + pv1[r + 8]);
#pragma unroll
    for (int st = 4; st > 0; st >>= 1)
#pragma unroll
      for (int r = 0; r < 4; r++)
        if (r < st) sum[r] = sum[r] + sum[r + st];
    l += sum[0] + __shfl_xor(sum[0], 32);

    // ---- P -> bf16 A-frags: direct pack (V rows sigma-permuted), PV ----
    unsigned W0[8], W1[8];
#pragma unroll
    for (int i = 0; i < 8; i++) {
      W0[i] = pkbf2(pv0[2 * i], pv0[2 * i + 1]);
      W1[i] = pkbf2(pv1[2 * i], pv1[2 * i + 1]);
    }
#pragma unroll
    for (int kt = 0; kt < 2; kt++) {
#pragma unroll
      for (int hc = 0; hc < 2; hc++) {
        union { unsigned u[4]; bf16x8 v; } fr;
#pragma unroll
        for (int mm = 0; mm < 4; mm++)
          fr.u[mm] = kt ? W1[hc * 4 + mm] : W0[hc * 4 + mm];
        const int ko = kt * 64 + hc * 32 + hi * 16;
        __builtin_amdgcn_s_setprio(1);
#pragma unroll
        for (int dt = 0; dt < 4; dt++) {
          const int row = dt * 32 + l31;
          const int swz = (((row >> 3) ^ row) & 7) << 4;
          const bf16x8 vf = *(const bf16x8*)(bV + row * 128 + (ko ^ swz));
          o[dt] = MFMA32(fr.v, vf, o[dt]);
        }
        __builtin_amdgcn_s_setprio(0);
      }
    }
  }

  // ---- epilogue: softmax complete per wave; write directly ----
  const float ri = 1.0f / l;
#pragma unroll
  for (int r = 0; r < 16; r++) {
    const int q = (r & 3) + 8 * (r >> 2) + 4 * hi;
    const float rr = __shfl(ri, q);
#pragma unroll
    for (int dt = 0; dt < 4; dt++)
      aout[(size_t)(qrow0 + q) * HID_ + h * DH + dt * 32 + l31] = f2bf(o[dt][r] * rr);
  }
}

extern "C" void kernel_launch(void* const* d_in, const int* in_sizes, int n_in,
                              void* d_out, int out_size, void* d_ws, size_t ws_size,
                              hipStream_t stream) {
  const float* hs = (const float*)d_in[0];
  const float* wq = (const float*)d_in[1];
  const float* wk = (const float*)d_in[2];
  const float* wv = (const float*)d_in[3];
  const float* wo = (const float*)d_in[4];
  const int* pos = (const int*)d_in[5];
  float* out = (float*)d_out;

  const size_t SZ_HS = (size_t)T_ * HID_;
  const size_t SZ_WQ = (size_t)HID_ * HID_;
  const size_t SZ_W1 = (size_t)QKVW * HID_;
  const size_t SZ_QKV = (size_t)T_ * QKVW;

  short* hs_bf = (short*)d_ws;
  short* w1_bf = hs_bf + SZ_HS;
  short* wo_bf = w1_bf + SZ_W1;
  short* qkv = wo_bf + SZ_WQ;
  short* attn = qkv + SZ_QKV;

  // one fused fp32->bf16 conversion for hs + all weights
  cvt_all<<<2048, 256, 0, stream>>>(hs, wq, wk, wv, wo, hs_bf, w1_bf, wo_bf);

  // QKV projection: (4096 x 2048) * (3072 x 2048)^T -> qkv bf16
  gemm_bt<1><<<dim3(T_ / 128, QKVW / 128), 256, 0, stream>>>(hs_bf, w1_bf, qkv, QKVW, HID_);

  // RoPE on Q (16 heads, pre-scaled) + K (4 heads), in place
  rope_k<<<dim3(T_), 320, 0, stream>>>(qkv, pos);

  // causal GQA flash attention -> attn bf16 (T, 2048)
  attn_k<<<dim3(512), 256, 0, stream>>>(qkv, attn);

  // output projection: (4096 x 2048) * (2048 x 2048)^T -> fp32 out
  gemm_bt<0><<<dim3(T_ / 128, HID_ / 128), 256, 0, stream>>>(attn, wo_bf, out, HID_, HID_);
}

// Round 15
// 251.454 us; speedup vs baseline: 1.1687x; 1.1687x over previous
//
#include <hip/hip_runtime.h>
#include <hip/hip_bf16.h>
#include <cstdint>

#define T_    4096
#define HID_  2048
#define DH    128
#define NQ_   16
#define NKV_  4
#define QKVW  3072   // 2048 Q + 512 K + 512 V

typedef __attribute__((ext_vector_type(8))) short bf16x8;
typedef __attribute__((ext_vector_type(4))) float f32x4;
typedef __attribute__((ext_vector_type(16))) float f32x16;
typedef __attribute__((ext_vector_type(4))) float f4;
typedef __attribute__((ext_vector_type(4))) short s4;

__device__ __forceinline__ short f2bf(float f) {
  union { float f; unsigned u; } x; x.f = f;
  unsigned r = x.u + 0x7fffu + ((x.u >> 16) & 1u);
  return (short)(r >> 16);
}
__device__ __forceinline__ float bf2f(short s) {
  return __uint_as_float(((unsigned)(unsigned short)s) << 16);
}
__device__ __forceinline__ unsigned pkbf2(float a, float b) {
  union { __hip_bfloat162 h; unsigned u; } c;
  c.h = __float22bfloat162_rn(make_float2(a, b));
  return c.u;
}

__device__ __forceinline__ void gload16(const void* g, void* l) {
  __builtin_amdgcn_global_load_lds(
      (const __attribute__((address_space(1))) unsigned*)g,
      (__attribute__((address_space(3))) unsigned*)l, 16, 0, 0);
}

#define MFMA16(a, b, c) __builtin_amdgcn_mfma_f32_16x16x32_bf16(a, b, c, 0, 0, 0)
#define MFMA32(a, b, c) __builtin_amdgcn_mfma_f32_32x32x16_bf16(a, b, c, 0, 0, 0)

#define Z16 {0.f,0.f,0.f,0.f,0.f,0.f,0.f,0.f,0.f,0.f,0.f,0.f,0.f,0.f,0.f,0.f}
#define SCL2 0.127517432f  // (1/sqrt(128)) * log2(e), folded into Q at RoPE

// ---------------- single fused fp32 -> bf16 conversion for all 5 tensors ----------------
#define C_HS 2097152u            // hs:  8M elems
#define C_WQ (C_HS + 1048576u)   // wq:  4M
#define C_WK (C_WQ + 262144u)    // wk:  1M
#define C_WV (C_WK + 262144u)    // wv:  1M
#define C_WO (C_WV + 1048576u)   // wo:  4M
__global__ void cvt_all(const float* __restrict__ hs, const float* __restrict__ wq,
                        const float* __restrict__ wk, const float* __restrict__ wv,
                        const float* __restrict__ wo, short* __restrict__ hs_bf,
                        short* __restrict__ w1_bf, short* __restrict__ wo_bf) {
  const unsigned stride = gridDim.x * blockDim.x;
  for (unsigned i = blockIdx.x * blockDim.x + threadIdx.x; i < C_WO; i += stride) {
    const float* s; short* d; unsigned off;
    if (i < C_HS)      { s = hs; d = hs_bf;           off = i; }
    else if (i < C_WQ) { s = wq; d = w1_bf;           off = i - C_HS; }
    else if (i < C_WK) { s = wk; d = w1_bf + 4194304; off = i - C_WQ; }
    else if (i < C_WV) { s = wv; d = w1_bf + 5242880; off = i - C_WK; }
    else               { s = wo; d = wo_bf;           off = i - C_WV; }
    f4 v = ((const f4*)s)[off];
    s4 o;
    o[0] = f2bf(v[0]); o[1] = f2bf(v[1]); o[2] = f2bf(v[2]); o[3] = f2bf(v[3]);
    ((s4*)d)[off] = o;
  }
}

// ---------------- GEMM: C = A (MxK) * B^T, B stored (N,K) row-major ----------------
// 128x128 tile, BK=64. LDS XOR-swizzled via pre-swizzled global_load_lds source.
template <int BF16OUT>
__global__ __launch_bounds__(256) void gemm_bt(const short* __restrict__ A,
                                               const short* __restrict__ B,
                                               void* __restrict__ Cp,
                                               int N, int K) {
  __shared__ short lA[128 * 64];
  __shared__ short lB[128 * 64];
  const int nb = gridDim.x * gridDim.y;
  const int lin = blockIdx.y * gridDim.x + blockIdx.x;
  const int per = nb >> 3;
  const int wg = (lin & 7) * per + (lin >> 3);
  const int bx = wg % gridDim.x;
  const int by = wg / gridDim.x;

  const int tid = threadIdx.x;
  const int lane = tid & 63;
  const int w = tid >> 6;
  const int wr = w >> 1, wc = w & 1;
  const int l15 = lane & 15, l4 = lane >> 4;
  f32x4 acc[4][4];
#pragma unroll
  for (int m = 0; m < 4; m++)
#pragma unroll
    for (int n = 0; n < 4; n++) acc[m][n] = f32x4{0.f, 0.f, 0.f, 0.f};

  const short* Ag = A + (size_t)bx * 128 * K;
  const short* Bg = B + (size_t)by * 128 * K;

  for (int kt = 0; kt < K; kt += 64) {
#pragma unroll
    for (int i = 0; i < 4; ++i) {
      const int cb = i * 256 + w * 64;       // wave-uniform chunk base
      const int c = cb + lane;
      const int row = c >> 3;                // 8 chunks (128B) per row
      const int x = (c & 7) << 4;            // byte col in LDS
      const int sx = x ^ ((row & 7) << 4);   // pre-swizzled source col
      gload16(Ag + (size_t)row * K + kt + (sx >> 1), (char*)lA + cb * 16);
      gload16(Bg + (size_t)row * K + kt + (sx >> 1), (char*)lB + cb * 16);
    }
    __syncthreads();
    bf16x8 af[4][2], bfr[4][2];
#pragma unroll
    for (int m = 0; m < 4; m++) {
      const int row = wr * 64 + m * 16 + l15;
      const int sw = (row & 7) << 4;
#pragma unroll
      for (int kk = 0; kk < 2; kk++)
        af[m][kk] = *(const bf16x8*)((const char*)lA + row * 128 + ((kk * 64 + l4 * 16) ^ sw));
    }
#pragma unroll
    for (int n = 0; n < 4; n++) {
      const int row = wc * 64 + n * 16 + l15;
      const int sw = (row & 7) << 4;
#pragma unroll
      for (int kk = 0; kk < 2; kk++)
        bfr[n][kk] = *(const bf16x8*)((const char*)lB + row * 128 + ((kk * 64 + l4 * 16) ^ sw));
    }
#pragma unroll
    for (int m = 0; m < 4; m++)
#pragma unroll
      for (int n = 0; n < 4; n++) {
        acc[m][n] = MFMA16(af[m][0], bfr[n][0], acc[m][n]);
        acc[m][n] = MFMA16(af[m][1], bfr[n][1], acc[m][n]);
      }
    __syncthreads();
  }

  const int r0 = bx * 128 + wr * 64;
  const int c0 = by * 128 + wc * 64;
#pragma unroll
  for (int m = 0; m < 4; m++)
#pragma unroll
    for (int n = 0; n < 4; n++)
#pragma unroll
      for (int r = 0; r < 4; r++) {
        const int row = r0 + m * 16 + l4 * 4 + r;
        const int col = c0 + n * 16 + l15;
        if (BF16OUT)
          ((short*)Cp)[(size_t)row * N + col] = f2bf(acc[m][n][r]);
        else
          ((float*)Cp)[(size_t)row * N + col] = acc[m][n][r];
      }
}

// ---------------- RoPE v2: per-row LDS sincos table + short4 vector I/O ----------------
__global__ void rope_k(short* __restrict__ qkv, const int* __restrict__ pos) {
  __shared__ float cs[64], sn[64];
  const int row = blockIdx.x;
  const int tid = threadIdx.x;
  if (tid < 64) {
    const float fp = (float)pos[row];
    const float freq = fp * powf(10000.0f, -(float)tid * (1.0f / 64.0f));
    cs[tid] = cosf(freq);
    sn[tid] = sinf(freq);
  }
  __syncthreads();
  const int p = tid * 4;              // pair index: 0..1279
  const int head = p >> 6;            // 0..19 : 16 Q heads then 4 K heads
  const int d0 = p & 63;
  const int col0 = (head < NQ_) ? head * DH : HID_ + (head - NQ_) * DH;
  const float scl = (head < NQ_) ? SCL2 : 1.0f;
  short* q = qkv + (size_t)row * QKVW + col0 + d0;
  s4 x1 = *(const s4*)q;
  s4 x2 = *(const s4*)(q + 64);
  s4 o1, o2;
#pragma unroll
  for (int j = 0; j < 4; j++) {
    const float c = cs[d0 + j], s = sn[d0 + j];
    const float a = bf2f(x1[j]), b = bf2f(x2[j]);
    o1[j] = f2bf((a * c - b * s) * scl);
    o2[j] = f2bf((b * c + a * s) * scl);
  }
  *(s4*)q = o1;
  *(s4*)(q + 64) = o2;
}

// ---------------- causal GQA flash attention (v10: balanced CU block pairs) ----------------
// 512 blocks x 512 threads, 2/CU. 8 waves = 4 heads x 2 KV-splits. Single 64KB
// staging buffer + reg prefetch one supertile ahead. qb: lin<256 -> base,
// lin>=256 -> 127-base (CU pair sums constant). Proven 129us / 253 total (R13).
#define PRE(j)                                                                      \
  {                                                                                 \
    const int kv0e = (j) * 128, kv0o = (j) * 128 + 64;                              \
    _Pragma("unroll") for (int i = 0; i < 2; i++) {                                 \
      const int idx_ = i * 512 + tid;                                               \
      const int row = idx_ >> 4, e = (idx_ & 15) << 3;                              \
      kre[i] = *(const bf16x8*)(kbase + (size_t)(kv0e + row) * QKVW + e);           \
      kro[i] = *(const bf16x8*)(kbase + (size_t)(kv0o + row) * QKVW + e);           \
    }                                                                               \
    {                                                                               \
      const int rp = tid >> 4, e = (tid & 15) << 3;                                 \
      vre[0] = *(const bf16x8*)(vbase + (size_t)(kv0e + 2 * rp) * QKVW + e);        \
      vre[1] = *(const bf16x8*)(vbase + (size_t)(kv0e + 2 * rp + 1) * QKVW + e);    \
      vro[0] = *(const bf16x8*)(vbase + (size_t)(kv0o + 2 * rp) * QKVW + e);        \
      vro[1] = *(const bf16x8*)(vbase + (size_t)(kv0o + 2 * rp + 1) * QKVW + e);    \
    }                                                                               \
  }

#define WRITEBUF(bufp)                                                          \
  {                                                                             \
    char* sKe_ = (bufp);                                                        \
    char* sKo_ = (bufp) + 16384;                                                \
    char* sVe_ = (bufp) + 32768;                                                \
    char* sVo_ = (bufp) + 49152;                                                \
    _Pragma("unroll") for (int i = 0; i < 2; i++) {                             \
      const int idx_ = i * 512 + tid;                                           \
      const int row = idx_ >> 4, e16 = (idx_ & 15) << 4;                        \
      const int swz = (((row >> 3) ^ row) & 7) << 4;                            \
      *(bf16x8*)(sKe_ + row * 256 + (e16 ^ swz)) = kre[i];                      \
      *(bf16x8*)(sKo_ + row * 256 + (e16 ^ swz)) = kro[i];                      \
    }                                                                           \
    {                                                                           \
      const int rp = tid >> 4, e = (tid & 15) << 3;                             \
      const int rp2 = (rp & ~6) | ((rp & 2) << 1) | ((rp & 4) >> 1);            \
      _Pragma("unroll") for (int jj = 0; jj < 8; jj++) {                        \
        const int d = e + jj;                                                   \
        const int swz = (((d >> 3) ^ d) & 7) << 4;                              \
        const unsigned pe = ((unsigned)(unsigned short)vre[0][jj]) |            \
                            (((unsigned)(unsigned short)vre[1][jj]) << 16);     \
        const unsigned po = ((unsigned)(unsigned short)vro[0][jj]) |            \
                            (((unsigned)(unsigned short)vro[1][jj]) << 16);     \
        *(unsigned*)(sVe_ + d * 128 + ((rp2 * 4) ^ swz)) = pe;                  \
        *(unsigned*)(sVo_ + d * 128 + ((rp2 * 4) ^ swz)) = po;                  \
      }                                                                         \
    }                                                                           \
  }

__global__ __launch_bounds__(512) void attn_k(const short* __restrict__ qkv,
                                              short* __restrict__ aout) {
  __shared__ __align__(16) char smem[67584];  // 64KB staging (reused for O-merge) + 2KB ml
  float* ml = (float*)(smem + 65536);  // [head][sp][2][32]

  const int lin = blockIdx.x;                 // 0..511
  const int xcd = lin & 7;
  const int kvh = xcd >> 1;                   // 2 XCDs per kvh
  const int up = (lin >> 8) & 1;
  const int idx = (lin >> 3) & 31;            // 0..31
  const int base = idx * 2 + (xcd & 1);       // 0..63
  const int qb = up ? (127 - base) : base;    // CU pair sums to 127
  const int tid = threadIdx.x, lane = tid & 63, w = tid >> 6;
  const int head = w & 3, sp = w >> 2;
  const int hi = lane >> 5, l31 = lane & 31;
  const int h = kvh * 4 + head;

  const short* kbase = qkv + HID_ + kvh * DH;
  const short* vbase = qkv + HID_ + NKV_ * DH + kvh * DH;
  const int spoff = sp ? 16384 : 0;

  const int qrow0 = qb * 32;
  const int ntiles = qb / 2 + 1;
  const int nsuper = (ntiles + 1) >> 1;
  const int myq = qrow0 + l31;

  bf16x8 qf[8];
  {
    const short* qp = qkv + (size_t)myq * QKVW + h * DH + hi * 8;
#pragma unroll
    for (int c = 0; c < 8; c++) qf[c] = *(const bf16x8*)(qp + c * 16);
  }
  f32x16 o[4] = {Z16, Z16, Z16, Z16};
  float m = -3e38f, l = 0.f;

  bf16x8 kre[2], kro[2], vre[2], vro[2];
  PRE(0)

  for (int j = 0; j < nsuper; ++j) {
    __syncthreads();  // all waves done reading previous supertile
    WRITEBUF(smem)
    __syncthreads();  // staged supertile visible
    if (j + 1 < nsuper) PRE(j + 1)  // overlaps compute below
    const char* bK = smem + spoff;
    const char* bV = smem + 32768 + spoff;

    const int t = 2 * j + sp;
    if (t < ntiles) {
      const int kv0 = t * 64;
      f32x16 s0 = Z16, s1 = Z16;
      const int sw0 = (((l31 >> 3) ^ l31) & 7) << 4;
      const int r1 = 32 + l31;
      const int sw1 = (((r1 >> 3) ^ r1) & 7) << 4;
      __builtin_amdgcn_s_setprio(1);
#pragma unroll
      for (int c = 0; c < 8; c++) {
        const int co = c * 32 + hi * 16;
        const bf16x8 k0 = *(const bf16x8*)(bK + l31 * 256 + (co ^ sw0));
        const bf16x8 k1 = *(const bf16x8*)(bK + r1 * 256 + (co ^ sw1));
        s0 = MFMA32(k0, qf[c], s0);
        s1 = MFMA32(k1, qf[c], s1);
      }
      __builtin_amdgcn_s_setprio(0);
      float sv0[16], sv1[16];
      if (t == ntiles - 1) {
#pragma unroll
        for (int r = 0; r < 16; r++) {
          const int kk = (r & 3) + 8 * (r >> 2) + 4 * hi;
          sv0[r] = (kv0 + kk <= myq) ? s0[r] : -1e30f;
          sv1[r] = (kv0 + 32 + kk <= myq) ? s1[r] : -1e30f;
        }
      } else {
#pragma unroll
        for (int r = 0; r < 16; r++) {
          sv0[r] = s0[r];
          sv1[r] = s1[r];
        }
      }
      float mx[8];
#pragma unroll
      for (int r = 0; r < 8; r++)
        mx[r] = fmaxf(fmaxf(sv0[r], sv0[r + 8]), fmaxf(sv1[r], sv1[r + 8]));
#pragma unroll
      for (int st = 4; st > 0; st >>= 1)
#pragma unroll
        for (int r = 0; r < 4; r++)
          if (r < st) mx[r] = fmaxf(mx[r], mx[r + st]);
      float pm = fmaxf(mx[0], __shfl_xor(mx[0], 32));
      if (__any(pm > m + 11.5f)) {  // defer-max (T13)
        const float mn = fmaxf(m, pm);
        const float al = exp2f(m - mn);
        m = mn;
        l *= al;
#pragma unroll
        for (int r = 0; r < 16; r++) {
          const float ar = __shfl(al, (r & 3) + 8 * (r >> 2) + 4 * hi);
#pragma unroll
          for (int dt = 0; dt < 4; dt++) o[dt][r] *= ar;
        }
      }
      float pv0[16], pv1[16];
#pragma unroll
      for (int r = 0; r < 16; r++) {
        pv0[r] = exp2f(sv0[r] - m);
        pv1[r] = exp2f(sv1[r] - m);
      }
      float sum[8];
#pragma unroll
      for (int r = 0; r < 8; r++)
        sum[r] = (pv0[r] + pv0[r + 8]) + (pv1[r] + pv1[r + 8]);
#pragma unroll
      for (int st = 4; st > 0; st >>= 1)
#pragma unroll
        for (int r = 0; r < 4; r++)
          if (r < st) sum[r] = sum[r] + sum[r + st];
      l += sum[0] + __shfl_xor(sum[0], 32);

      unsigned W0[8], W1[8];
#pragma unroll
      for (int i = 0; i < 8; i++) {
        W0[i] = pkbf2(pv0[2 * i], pv0[2 * i + 1]);
        W1[i] = pkbf2(pv1[2 * i], pv1[2 * i + 1]);
      }
#pragma unroll
      for (int kt = 0; kt < 2; kt++) {
#pragma unroll
        for (int hc = 0; hc < 2; hc++) {
          union { unsigned u[4]; bf16x8 v; } fr;
#pragma unroll
          for (int mm = 0; mm < 4; mm++)
            fr.u[mm] = kt ? W1[hc * 4 + mm] : W0[hc * 4 + mm];
          const int ko = kt * 64 + hc * 32 + hi * 16;
          __builtin_amdgcn_s_setprio(1);
#pragma unroll
          for (int dt = 0; dt < 4; dt++) {
            const int row = dt * 32 + l31;
            const int swz = (((row >> 3) ^ row) & 7) << 4;
            const bf16x8 vf = *(const bf16x8*)(bV + row * 128 + (ko ^ swz));
            o[dt] = MFMA32(fr.v, vf, o[dt]);
          }
          __builtin_amdgcn_s_setprio(0);
        }
      }
    }
  }

  // ---- merge the two KV-splits of each head, write out ----
  if (lane < 32) {
    ml[((head * 2 + sp) * 2) * 32 + lane] = m;
    ml[((head * 2 + sp) * 2 + 1) * 32 + lane] = l;
  }
  __syncthreads();  // also: all compute reads of staging buffer done
  const float mo = ml[((head * 2 + (1 - sp)) * 2) * 32 + l31];
  const float lo = ml[((head * 2 + (1 - sp)) * 2 + 1) * 32 + l31];
  const float M = fmaxf(m, mo);
  const float aown = exp2f(m - M);
  const float ltot = l * aown + lo * exp2f(mo - M);
#pragma unroll
  for (int r = 0; r < 16; r++) {
    const float ar = __shfl(aown, (r & 3) + 8 * (r >> 2) + 4 * hi);
#pragma unroll
    for (int dt = 0; dt < 4; dt++) o[dt][r] *= ar;
  }
  float* Ob = (float*)smem + head * 4096;  // [32 q][128 d], reuses staging buffer
  if (sp == 1) {
#pragma unroll
    for (int r = 0; r < 16; r++) {
      const int q = (r & 3) + 8 * (r >> 2) + 4 * hi;
#pragma unroll
      for (int dt = 0; dt < 4; dt++) Ob[q * 128 + dt * 32 + l31] = o[dt][r];
    }
  }
  __syncthreads();
  if (sp == 0) {
    const float ri = 1.0f / ltot;
#pragma unroll
    for (int r = 0; r < 16; r++) {
      const float rr = __shfl(ri, (r & 3) + 8 * (r >> 2) + 4 * hi);
      const int q = (r & 3) + 8 * (r >> 2) + 4 * hi;
#pragma unroll
      for (int dt = 0; dt < 4; dt++) {
        const float val = (o[dt][r] + Ob[q * 128 + dt * 32 + l31]) * rr;
        aout[(size_t)(qrow0 + q) * HID_ + h * DH + dt * 32 + l31] = f2bf(val);
      }
    }
  }
}

extern "C" void kernel_launch(void* const* d_in, const int* in_sizes, int n_in,
                              void* d_out, int out_size, void* d_ws, size_t ws_size,
                              hipStream_t stream) {
  const float* hs = (const float*)d_in[0];
  const float* wq = (const float*)d_in[1];
  const float* wk = (const float*)d_in[2];
  const float* wv = (const float*)d_in[3];
  const float* wo = (const float*)d_in[4];
  const int* pos = (const int*)d_in[5];
  float* out = (float*)d_out;

  const size_t SZ_HS = (size_t)T_ * HID_;
  const size_t SZ_WQ = (size_t)HID_ * HID_;
  const size_t SZ_W1 = (size_t)QKVW * HID_;
  const size_t SZ_QKV = (size_t)T_ * QKVW;

  short* hs_bf = (short*)d_ws;
  short* w1_bf = hs_bf + SZ_HS;
  short* wo_bf = w1_bf + SZ_W1;
  short* qkv = wo_bf + SZ_WQ;
  short* attn = qkv + SZ_QKV;

  // one fused fp32->bf16 conversion for hs + all weights
  cvt_all<<<2048, 256, 0, stream>>>(hs, wq, wk, wv, wo, hs_bf, w1_bf, wo_bf);

  // QKV projection: (4096 x 2048) * (3072 x 2048)^T -> qkv bf16
  gemm_bt<1><<<dim3(T_ / 128, QKVW / 128), 256, 0, stream>>>(hs_bf, w1_bf, qkv, QKVW, HID_);

  // RoPE on Q (16 heads, pre-scaled) + K (4 heads), in place
  rope_k<<<dim3(T_), 320, 0, stream>>>(qkv, pos);

  // causal GQA flash attention -> attn bf16 (T, 2048)
  attn_k<<<dim3(512), 512, 0, stream>>>(qkv, attn);

  // output projection: (4096 x 2048) * (2048 x 2048)^T -> fp32 out
  gemm_bt<0><<<dim3(T_ / 128, HID_ / 128), 256, 0, stream>>>(attn, wo_bf, out, HID_, HID_);
}